// Round 1
// baseline (12837.090 us; speedup 1.0000x reference)
//
#include <hip/hip_runtime.h>
#include <hip/hip_bf16.h>
#include <cmath>

#define N_ATOMS 65536
#define N_BONDS 98304
#define N_MOLS  4096
#define D_IN    128
#define DD      256
#define REPEAT  3

// ---------------------------------------------------------------------------
// Generic concat-gather GEMM + tanh, in-place-safe.
//   out[m, :] = tanh( concat_{seg}( src_seg[ row_seg(m), 0:SEGW ] ) @ W )
// row_seg(m) = idx_seg ? idx_seg[m] : m.
// Each block owns 64 full rows (all 256 output cols) -> in-place update of
// src0==out is race-free (reads of own rows finish before epilogue writes;
// no other block reads these rows of the in-place tensor).
// BM=64, BN=256, BK=16. 256 threads, 8x8 acc/thread.
// ---------------------------------------------------------------------------
template<int NSEG, int SEGW>
__global__ __launch_bounds__(256)
void concat_gemm_tanh(const float* __restrict__ s0, const int* __restrict__ i0,
                      const float* __restrict__ s1, const int* __restrict__ i1,
                      const float* __restrict__ s2, const int* __restrict__ i2,
                      const float* __restrict__ s3, const int* __restrict__ i3,
                      const float* __restrict__ s4, const int* __restrict__ i4,
                      const float* __restrict__ W,
                      float* __restrict__ out, float* __restrict__ out2)
{
  // A tile [64 rows][16 k] padded to 20 floats/row: 80B row stride keeps
  // float4 stores 16B-aligned; inner reads are 2-way broadcast (free).
  __shared__ __align__(16) float As[64 * 20];
  __shared__ __align__(16) float Bs[16 * 256];

  const int tid = threadIdx.x;
  const int m0  = blockIdx.x * 64;
  const int ml  = tid >> 2;          // 0..63  A-load row
  const int kl  = (tid & 3) << 2;    // 0,4,8,12 A-load k offset
  const int cg  = tid & 31;          // column group: owns cols cg + 32*j
  const int rg  = tid >> 5;          // 0..7 row group: owns rows rg*8 + i

  float acc[8][8];
  #pragma unroll
  for (int i = 0; i < 8; ++i)
    #pragma unroll
    for (int j = 0; j < 8; ++j)
      acc[i][j] = 0.0f;

  #pragma unroll
  for (int seg = 0; seg < NSEG; ++seg) {
    const float* sp = seg == 0 ? s0 : seg == 1 ? s1 : seg == 2 ? s2 : seg == 3 ? s3 : s4;
    const int*   ip = seg == 0 ? i0 : seg == 1 ? i1 : seg == 2 ? i2 : seg == 3 ? i3 : i4;
    int row = m0 + ml;
    if (ip) row = ip[row];
    const float* arow = sp + (size_t)row * SEGW;

    for (int t = 0; t < SEGW / 16; ++t) {
      const int ktb = seg * SEGW + t * 16;
      // stage B tile [16][256] (linear, coalesced, conflict-free)
      const float* wp = W + (size_t)ktb * DD;
      #pragma unroll
      for (int p = 0; p < 4; ++p)
        *(float4*)&Bs[p * 1024 + tid * 4] = *(const float4*)&wp[p * 1024 + tid * 4];
      // stage A tile (gathered rows; 4 contiguous floats/thread of one row)
      *(float4*)&As[ml * 20 + kl] = *(const float4*)&arow[t * 16 + kl];
      __syncthreads();

      #pragma unroll
      for (int k = 0; k < 16; ++k) {
        float a[8], b[8];
        #pragma unroll
        for (int i = 0; i < 8; ++i) a[i] = As[(rg * 8 + i) * 20 + k];
        #pragma unroll
        for (int j = 0; j < 8; ++j) b[j] = Bs[k * 256 + cg + 32 * j];
        #pragma unroll
        for (int i = 0; i < 8; ++i)
          #pragma unroll
          for (int j = 0; j < 8; ++j)
            acc[i][j] = fmaf(a[i], b[j], acc[i][j]);
      }
      __syncthreads();
    }
  }

  #pragma unroll
  for (int i = 0; i < 8; ++i) {
    const size_t r = (size_t)(m0 + rg * 8 + i) * DD;
    #pragma unroll
    for (int j = 0; j < 8; ++j) {
      float v = tanhf(acc[i][j]);
      out[r + cg + 32 * j] = v;
      if (out2) out2[r + cg + 32 * j] = v;
    }
  }
}

// h_e0[b][c] = tanh(bond_orders[b] * W_fe[c]); also seeds h_e (d_out).
__global__ __launch_bounds__(256)
void init_he0(const float* __restrict__ bo, const float* __restrict__ wfe,
              float* __restrict__ he0, float* __restrict__ he)
{
  int t = blockIdx.x * 256 + threadIdx.x;     // N_BONDS*64 threads
  int b = t >> 6;
  int c = (t & 63) << 2;
  float o = bo[b];
  float4 w = *(const float4*)&wfe[c];
  float4 v;
  v.x = tanhf(o * w.x); v.y = tanhf(o * w.y);
  v.z = tanhf(o * w.z); v.w = tanhf(o * w.w);
  size_t idx = (size_t)b * DD + c;
  *(float4*)&he0[idx] = v;
  *(float4*)&he[idx]  = v;
}

// e_bar_v[src[b]] += h_e[b]; e_bar_v[dst[b]] += h_e[b]
__global__ __launch_bounds__(256)
void scatter_edge_to_atoms(const float* __restrict__ he, const int* __restrict__ src,
                           const int* __restrict__ dst, float* __restrict__ ebv)
{
  int t = blockIdx.x * 256 + threadIdx.x;     // N_BONDS*64 threads
  int b = t >> 6;
  int c = (t & 63) << 2;
  float4 v = *(const float4*)&he[(size_t)b * DD + c];
  int s = src[b], d = dst[b];
  float* ps = &ebv[(size_t)s * DD + c];
  float* pd = &ebv[(size_t)d * DD + c];
  unsafeAtomicAdd(ps + 0, v.x); unsafeAtomicAdd(ps + 1, v.y);
  unsafeAtomicAdd(ps + 2, v.z); unsafeAtomicAdd(ps + 3, v.w);
  unsafeAtomicAdd(pd + 0, v.x); unsafeAtomicAdd(pd + 1, v.y);
  unsafeAtomicAdd(pd + 2, v.z); unsafeAtomicAdd(pd + 3, v.w);
}

// out[ids[r]] += x[r]   (rows of width 256)
__global__ __launch_bounds__(256)
void seg_sum_rows(const float* __restrict__ x, const int* __restrict__ ids,
                  float* __restrict__ out)
{
  int t = blockIdx.x * 256 + threadIdx.x;     // rows*64 threads
  int r = t >> 6;
  int c = (t & 63) << 2;
  float4 v = *(const float4*)&x[(size_t)r * DD + c];
  int m = ids[r];
  float* p = &out[(size_t)m * DD + c];
  unsafeAtomicAdd(p + 0, v.x); unsafeAtomicAdd(p + 1, v.y);
  unsafeAtomicAdd(p + 2, v.z); unsafeAtomicAdd(p + 3, v.w);
}

// msum[mol] += atoms[a] (width 128); cnt[mol] += 1
__global__ __launch_bounds__(256)
void mol_accum(const float* __restrict__ atoms, const int* __restrict__ amol,
               float* __restrict__ msum, float* __restrict__ cnt)
{
  int t = blockIdx.x * 256 + threadIdx.x;     // N_ATOMS*32 threads
  int a = t >> 5;
  int c = (t & 31) << 2;
  float4 v = *(const float4*)&atoms[(size_t)a * D_IN + c];
  int m = amol[a];
  float* p = &msum[(size_t)m * D_IN + c];
  unsafeAtomicAdd(p + 0, v.x); unsafeAtomicAdd(p + 1, v.y);
  unsafeAtomicAdd(p + 2, v.z); unsafeAtomicAdd(p + 3, v.w);
  if ((t & 31) == 0) unsafeAtomicAdd(&cnt[m], 1.0f);
}

__global__ __launch_bounds__(256)
void mol_mean_k(const float* __restrict__ msum, const float* __restrict__ cnt,
                float* __restrict__ mmean)
{
  int t = blockIdx.x * 256 + threadIdx.x;     // N_MOLS*32 threads
  int m = t >> 5;
  int c = (t & 31) << 2;
  float inv = 1.0f / fmaxf(cnt[m], 1.0f);
  float4 v = *(const float4*)&msum[(size_t)m * D_IN + c];
  v.x *= inv; v.y *= inv; v.z *= inv; v.w *= inv;
  *(float4*)&mmean[(size_t)m * D_IN + c] = v;
}

extern "C" void kernel_launch(void* const* d_in, const int* in_sizes, int n_in,
                              void* d_out, int out_size, void* d_ws, size_t ws_size,
                              hipStream_t stream)
{
  const float* atoms       = (const float*)d_in[0];
  const float* bond_orders = (const float*)d_in[1];
  const int*   bond_src    = (const int*)d_in[2];
  const int*   bond_dst    = (const int*)d_in[3];
  const int*   atom_mol    = (const int*)d_in[4];
  const int*   bond_mol    = (const int*)d_in[5];
  const float* W_fe        = (const float*)d_in[6];
  const float* W_fv        = (const float*)d_in[7];
  const float* W_fu        = (const float*)d_in[8];
  const float* W_e         = (const float*)d_in[9];
  const float* W_v         = (const float*)d_in[10];
  const float* W_u         = (const float*)d_in[11];

  float* he = (float*)d_out;            // h_e lives in d_out across iterations
  float* ws = (float*)d_ws;
  size_t off = 0;
  float* he0  = ws + off; off += (size_t)N_BONDS * DD;   // 25165824
  float* hv   = ws + off; off += (size_t)N_ATOMS * DD;
  float* hv0  = ws + off; off += (size_t)N_ATOMS * DD;
  float* hu   = ws + off; off += (size_t)N_MOLS * DD;
  float* hu0  = ws + off; off += (size_t)N_MOLS * DD;
  float* ebv  = ws + off; off += (size_t)N_ATOMS * DD;   // ebv, eb, vb contiguous (single memset)
  float* eb   = ws + off; off += (size_t)N_MOLS * DD;
  float* vb   = ws + off; off += (size_t)N_MOLS * DD;
  float* msum = ws + off; off += (size_t)N_MOLS * D_IN;  // msum, cnt contiguous (single memset)
  float* cnt  = ws + off; off += N_MOLS;
  float* mmean= ws + off; off += (size_t)N_MOLS * D_IN;
  if (ws_size < off * sizeof(float)) return;   // ~323 MB required

  const float* NF = nullptr; const int* NI = nullptr;

  // ---- init: h_e0 (also seeds h_e), h_v0 (seeds h_v), h_u0 (seeds h_u) ----
  hipMemsetAsync(msum, 0, (size_t)(N_MOLS * D_IN + N_MOLS) * sizeof(float), stream);
  mol_accum<<<N_ATOMS * 32 / 256, 256, 0, stream>>>(atoms, atom_mol, msum, cnt);
  mol_mean_k<<<N_MOLS * 32 / 256, 256, 0, stream>>>(msum, cnt, mmean);
  init_he0<<<N_BONDS * 64 / 256, 256, 0, stream>>>(bond_orders, W_fe, he0, he);
  concat_gemm_tanh<1, 128><<<N_ATOMS / 64, 256, 0, stream>>>(
      atoms, NI, NF, NI, NF, NI, NF, NI, NF, NI, W_fv, hv0, hv);
  concat_gemm_tanh<1, 128><<<N_MOLS / 64, 256, 0, stream>>>(
      mmean, NI, NF, NI, NF, NI, NF, NI, NF, NI, W_fu, hu0, hu);

  // ---- 3 message-passing iterations ----
  for (int it = 0; it < REPEAT; ++it) {
    hipMemsetAsync(ebv, 0, (size_t)(N_ATOMS * DD + 2 * N_MOLS * DD) * sizeof(float), stream);
    // h_e = tanh([h_e, h_e0, h_v[src], h_v[dst], h_u[bond_mol]] @ W_e)   (in-place in d_out)
    concat_gemm_tanh<5, 256><<<N_BONDS / 64, 256, 0, stream>>>(
        he, NI, he0, NI, hv, bond_src, hv, bond_dst, hu, bond_mol, W_e, he, nullptr);
    scatter_edge_to_atoms<<<N_BONDS * 64 / 256, 256, 0, stream>>>(he, bond_src, bond_dst, ebv);
    seg_sum_rows<<<N_BONDS * 64 / 256, 256, 0, stream>>>(he, bond_mol, eb);
    // h_v = tanh([h_v, h_v0, e_bar_v, h_u[atom_mol]] @ W_v)              (in-place)
    concat_gemm_tanh<4, 256><<<N_ATOMS / 64, 256, 0, stream>>>(
        hv, NI, hv0, NI, ebv, NI, hu, atom_mol, NF, NI, W_v, hv, nullptr);
    seg_sum_rows<<<N_ATOMS * 64 / 256, 256, 0, stream>>>(hv, atom_mol, vb);
    // h_u = tanh([h_u, h_u0, e_bar, v_bar] @ W_u)                        (in-place)
    concat_gemm_tanh<4, 256><<<N_MOLS / 64, 256, 0, stream>>>(
        hu, NI, hu0, NI, eb, NI, vb, NI, NF, NI, W_u, hu, nullptr);
  }
}

// Round 3
// 3575.656 us; speedup vs baseline: 3.5901x; 3.5901x over previous
//
#include <hip/hip_runtime.h>
#include <cstdint>
#include <cmath>

#define N_ATOMS 65536
#define N_BONDS 98304
#define N_MOLS  4096
#define D_IN    128
#define DD      256
#define REPEAT  3

typedef __attribute__((ext_vector_type(8))) short short8;   // 8 f16 = 4 VGPR (guide §3)
typedef __attribute__((ext_vector_type(4))) float f32x4;
typedef unsigned short ushort_t;

__device__ __forceinline__ unsigned short f2h(float f) {    // RNE f32->f16
  union { _Float16 h; unsigned short u; } x; x.h = (_Float16)f; return x.u;
}
__device__ __forceinline__ float h2f(unsigned short u) {
  union { unsigned short u; _Float16 h; } x; x.u = u; return (float)x.h;
}

#define GLD16(gp, lp) __builtin_amdgcn_global_load_lds( \
    (const __attribute__((address_space(1))) void*)(gp), \
    (__attribute__((address_space(3))) void*)(lp), 16, 0, 0)

// ---------------------------------------------------------------------------
// MFMA concat-gather GEMM + tanh (fp16 in, f32 acc, fp16 out [+f32 out]).
//   out[m,:] = tanh( concat_seg( src_seg[row_seg(m), 0:SEGW] ) @ W ),  N = 256
// Wt is the fp16 TRANSPOSED weight: Wt[n][k], n<256, k<NSEG*SEGW.
// Full-N blocks (BN=256) -> in-place update of seg0==out is race-free.
// BM rows/block, 4 waves per 64 rows, wave tile 64x64, mfma 16x16x32 f16.
// LDS: A [BM][32] f16 (64B rows) + B(=Wt cols) [256][32] f16. XOR chunk
// swizzle f(r)=(r&3)^((r>>2)&3) applied to the GLOBAL source at stage time
// and to the ds_read address (both-sides, rule #21) -> 2-way alias (free).
// Functionally verified in R2 (bf16 version failed only on precision).
// ---------------------------------------------------------------------------
template<int NSEG, int SEGW, int BM>
__global__ __launch_bounds__(BM * 4)
void mfma_concat_gemm(const ushort_t* __restrict__ s0, const int* __restrict__ i0,
                      const ushort_t* __restrict__ s1, const int* __restrict__ i1,
                      const ushort_t* __restrict__ s2, const int* __restrict__ i2,
                      const ushort_t* __restrict__ s3, const int* __restrict__ i3,
                      const ushort_t* __restrict__ s4, const int* __restrict__ i4,
                      const ushort_t* __restrict__ Wt,
                      ushort_t* __restrict__ ob, ushort_t* __restrict__ ob2,
                      float* __restrict__ of)
{
  constexpr int NT     = BM * 4;           // threads
  constexpr int KW     = NSEG * SEGW;      // total K
  constexpr int SPS    = SEGW / 32;        // K-steps per segment
  constexpr int ABYTES = BM * 64;          // A tile bytes
  constexpr int BI     = 16384 / (NT * 16);// B stage instrs per thread

  __shared__ __align__(16) char smem[ABYTES + 16384];

  const int t      = threadIdx.x;
  const int m0     = blockIdx.x * BM;
  const int srcoff = (((t & 3) ^ ((t >> 2) & 3) ^ ((t >> 4) & 3)) << 4); // stage-side swizzled chunk
  const int toff   = t * 16;

  // per-thread gathered A-row byte offsets, one per segment
  uint32_t aoff[5];
  {
    const int rg = m0 + (t >> 2);
    const int* ips[5] = { i0, i1, i2, i3, i4 };
    #pragma unroll
    for (int s = 0; s < NSEG; ++s) {
      int idx = ips[s] ? ips[s][rg] : rg;
      aoff[s] = (uint32_t)idx * (SEGW * 2);
    }
  }

  // per-thread Wt (B) stage base pointers
  const char* wtb[4];
  #pragma unroll
  for (int i = 0; i < BI; ++i)
    wtb[i] = (const char*)Wt + (size_t)((i * (NT >> 2) + (t >> 2)) * KW) * 2 + srcoff;

  f32x4 acc[4][4];
  const f32x4 z = {0.f, 0.f, 0.f, 0.f};
  #pragma unroll
  for (int a = 0; a < 4; ++a)
    #pragma unroll
    for (int b = 0; b < 4; ++b) acc[a][b] = z;

  const int l   = t & 63;
  const int wid = t >> 6;
  const int wr  = wid >> 2;                 // 0..BM/64-1
  const int wc  = wid & 3;                  // 0..3 (col strip of 64)
  const int swz = (((l >> 4) ^ (l & 3) ^ ((l >> 2) & 3)) << 4); // read-side swizzled chunk
  const int aro = wr * 4096 + (l & 15) * 64 + swz;
  const int bro = ABYTES + wc * 4096 + (l & 15) * 64 + swz;

  int kt = 0;
  #pragma unroll
  for (int seg = 0; seg < NSEG; ++seg) {
    const ushort_t* sp = seg == 0 ? s0 : seg == 1 ? s1 : seg == 2 ? s2 : seg == 3 ? s3 : s4;
    const char* arow = (const char*)sp + aoff[seg];
    for (int sub = 0; sub < SPS; ++sub, ++kt) {
      // stage A (1 x 16B/thread) and B (BI x 16B/thread) via global_load_lds
      GLD16(arow + sub * 64 + srcoff, smem + toff);
      #pragma unroll
      for (int i = 0; i < BI; ++i)
        GLD16(wtb[i] + (size_t)kt * 64, smem + ABYTES + i * (NT * 16) + toff);
      __syncthreads();                       // compiler drains vmcnt before barrier

      short8 af[4], bfv[4];
      #pragma unroll
      for (int mf = 0; mf < 4; ++mf) af[mf]  = *(const short8*)(smem + aro + mf * 1024);
      #pragma unroll
      for (int nf = 0; nf < 4; ++nf) bfv[nf] = *(const short8*)(smem + bro + nf * 1024);
      #pragma unroll
      for (int mf = 0; mf < 4; ++mf)
        #pragma unroll
        for (int nf = 0; nf < 4; ++nf)
          acc[mf][nf] = __builtin_amdgcn_mfma_f32_16x16x32_f16(af[mf], bfv[nf], acc[mf][nf], 0, 0, 0);
      __syncthreads();                       // protect LDS before next stage
    }
  }

  // epilogue: C/D layout col=lane&15, row=(lane>>4)*4+reg (m89-verified, dtype-independent)
  const int colb = wc * 64 + (l & 15);
  const int rowb = m0 + wr * 64 + ((l >> 4) << 2);
  #pragma unroll
  for (int mf = 0; mf < 4; ++mf) {
    #pragma unroll
    for (int nf = 0; nf < 4; ++nf) {
      f32x4 d = acc[mf][nf];
      #pragma unroll
      for (int r = 0; r < 4; ++r) {
        float v = tanhf(d[r]);
        size_t o = (size_t)(rowb + mf * 16 + r) * DD + colb + nf * 16;
        unsigned short hv16 = f2h(v);
        ob[o] = hv16;
        if (ob2) ob2[o] = hv16;
        if (of)  of[o]  = v;
      }
    }
  }
}

// -------------------------- helper kernels ---------------------------------

__global__ __launch_bounds__(256)
void f32_to_f16(const float* __restrict__ in, ushort_t* __restrict__ out, int n4) {
  int t = blockIdx.x * 256 + threadIdx.x;
  if (t >= n4) return;
  float4 v = ((const float4*)in)[t];
  ushort4 o; o.x = f2h(v.x); o.y = f2h(v.y); o.z = f2h(v.z); o.w = f2h(v.w);
  ((ushort4*)out)[t] = o;
}

// in [K][256] f32  ->  out [256][K] f16
__global__ __launch_bounds__(256)
void transpose_w(const float* __restrict__ in, ushort_t* __restrict__ out, int K) {
  int t = blockIdx.x * 256 + threadIdx.x;   // t = n*K + k
  int n = t / K, k = t - n * K;
  out[t] = f2h(in[(size_t)k * DD + n]);
}

__global__ __launch_bounds__(256)
void init_he0_k(const float* __restrict__ bo, const float* __restrict__ wfe,
                ushort_t* __restrict__ he0, ushort_t* __restrict__ he) {
  int t = blockIdx.x * 256 + threadIdx.x;   // N_BONDS*64
  int b = t >> 6, c = (t & 63) << 2;
  float o = bo[b];
  float4 w = *(const float4*)&wfe[c];
  ushort4 v;
  v.x = f2h(tanhf(o * w.x)); v.y = f2h(tanhf(o * w.y));
  v.z = f2h(tanhf(o * w.z)); v.w = f2h(tanhf(o * w.w));
  size_t idx = ((size_t)b * DD + c) >> 2;
  ((ushort4*)he0)[idx] = v; ((ushort4*)he)[idx] = v;
}

__global__ __launch_bounds__(256)
void mol_accum(const float* __restrict__ atoms, const int* __restrict__ amol,
               float* __restrict__ msum, float* __restrict__ cnt) {
  int t = blockIdx.x * 256 + threadIdx.x;   // N_ATOMS*32
  int a = t >> 5, c = (t & 31) << 2;
  float4 v = *(const float4*)&atoms[(size_t)a * D_IN + c];
  int m = amol[a];
  float* p = &msum[(size_t)m * D_IN + c];
  unsafeAtomicAdd(p + 0, v.x); unsafeAtomicAdd(p + 1, v.y);
  unsafeAtomicAdd(p + 2, v.z); unsafeAtomicAdd(p + 3, v.w);
  if ((t & 31) == 0) unsafeAtomicAdd(&cnt[m], 1.0f);
}

__global__ __launch_bounds__(256)
void mol_mean_h(const float* __restrict__ msum, const float* __restrict__ cnt,
                ushort_t* __restrict__ mmean) {
  int t = blockIdx.x * 256 + threadIdx.x;   // N_MOLS*32
  int m = t >> 5, c = (t & 31) << 2;
  float inv = 1.0f / fmaxf(cnt[m], 1.0f);
  float4 v = *(const float4*)&msum[(size_t)m * D_IN + c];
  ushort4 o; o.x = f2h(v.x * inv); o.y = f2h(v.y * inv);
  o.z = f2h(v.z * inv); o.w = f2h(v.w * inv);
  ((ushort4*)mmean)[((size_t)m * D_IN + c) >> 2] = o;
}

// e_bar_v[src[b]] += h_e[b];  e_bar_v[dst[b]] += h_e[b]   (f16 read, f32 atomics)
__global__ __launch_bounds__(256)
void scatter_edge_h(const ushort_t* __restrict__ he, const int* __restrict__ src,
                    const int* __restrict__ dst, float* __restrict__ ebv) {
  int t = blockIdx.x * 256 + threadIdx.x;   // N_BONDS*64
  int b = t >> 6, c = (t & 63) << 2;
  ushort4 v = *(const ushort4*)&he[(size_t)b * DD + c];
  float x0 = h2f(v.x), x1 = h2f(v.y), x2 = h2f(v.z), x3 = h2f(v.w);
  int s = src[b], d = dst[b];
  float* ps = &ebv[(size_t)s * DD + c];
  float* pd = &ebv[(size_t)d * DD + c];
  unsafeAtomicAdd(ps + 0, x0); unsafeAtomicAdd(ps + 1, x1);
  unsafeAtomicAdd(ps + 2, x2); unsafeAtomicAdd(ps + 3, x3);
  unsafeAtomicAdd(pd + 0, x0); unsafeAtomicAdd(pd + 1, x1);
  unsafeAtomicAdd(pd + 2, x2); unsafeAtomicAdd(pd + 3, x3);
}

// out[ids[r]] += x[r] for SORTED ids: run-compress in registers, flush on change.
__global__ __launch_bounds__(256)
void seg_sum_sorted(const ushort_t* __restrict__ x, const int* __restrict__ ids,
                    float* __restrict__ out) {
  __shared__ int sid[64];
  int r0 = blockIdx.x * 64;
  int c  = threadIdx.x;                     // 256 threads = 256 cols
  if (c < 64) sid[c] = ids[r0 + c];
  __syncthreads();
  float acc = 0.f; int prev = sid[0];
  const ushort_t* p = x + (size_t)r0 * DD + c;
  for (int r = 0; r < 64; ++r, p += DD) {
    int id = sid[r];                        // wave-uniform
    if (id != prev) { unsafeAtomicAdd(&out[(size_t)prev * DD + c], acc); acc = 0.f; prev = id; }
    acc += h2f(*p);
  }
  unsafeAtomicAdd(&out[(size_t)prev * DD + c], acc);
}

// ---------------------------------------------------------------------------

extern "C" void kernel_launch(void* const* d_in, const int* in_sizes, int n_in,
                              void* d_out, int out_size, void* d_ws, size_t ws_size,
                              hipStream_t stream)
{
  const float* atoms       = (const float*)d_in[0];
  const float* bond_orders = (const float*)d_in[1];
  const int*   bond_src    = (const int*)d_in[2];
  const int*   bond_dst    = (const int*)d_in[3];
  const int*   atom_mol    = (const int*)d_in[4];
  const int*   bond_mol    = (const int*)d_in[5];
  const float* W_fe        = (const float*)d_in[6];
  const float* W_fv        = (const float*)d_in[7];
  const float* W_fu        = (const float*)d_in[8];
  const float* W_e         = (const float*)d_in[9];
  const float* W_v         = (const float*)d_in[10];
  const float* W_u         = (const float*)d_in[11];

  char* w = (char*)d_ws;
  auto alloc = [&](size_t bytes) { char* p = w; w += (bytes + 255) & ~(size_t)255; return p; };

  ushort_t* atoms_h  = (ushort_t*)alloc((size_t)N_ATOMS * D_IN * 2);
  ushort_t* he0  = (ushort_t*)alloc((size_t)N_BONDS * DD * 2);
  ushort_t* he   = (ushort_t*)alloc((size_t)N_BONDS * DD * 2);
  ushort_t* hv0  = (ushort_t*)alloc((size_t)N_ATOMS * DD * 2);
  ushort_t* hv   = (ushort_t*)alloc((size_t)N_ATOMS * DD * 2);
  ushort_t* hu0  = (ushort_t*)alloc((size_t)N_MOLS * DD * 2);
  ushort_t* hu   = (ushort_t*)alloc((size_t)N_MOLS * DD * 2);
  ushort_t* mmean= (ushort_t*)alloc((size_t)N_MOLS * D_IN * 2);
  ushort_t* Wte  = (ushort_t*)alloc((size_t)DD * 1280 * 2);
  ushort_t* Wtv  = (ushort_t*)alloc((size_t)DD * 1024 * 2);
  ushort_t* Wtu  = (ushort_t*)alloc((size_t)DD * 1024 * 2);
  ushort_t* Wtfv = (ushort_t*)alloc((size_t)DD * D_IN * 2);
  ushort_t* Wtfu = (ushort_t*)alloc((size_t)DD * D_IN * 2);
  float* ebv_f = (float*)alloc((size_t)N_ATOMS * DD * 4);   // ebv,eb,vb contiguous
  float* eb_f  = (float*)alloc((size_t)N_MOLS * DD * 4);
  float* vb_f  = (float*)alloc((size_t)N_MOLS * DD * 4);
  ushort_t* ebv_h = (ushort_t*)alloc((size_t)N_ATOMS * DD * 2);
  ushort_t* eb_h  = (ushort_t*)alloc((size_t)N_MOLS * DD * 2); // eb_h,vb_h contiguous
  ushort_t* vb_h  = (ushort_t*)alloc((size_t)N_MOLS * DD * 2);
  float* msum = (float*)alloc((size_t)N_MOLS * D_IN * 4);       // msum,cnt contiguous
  float* cnt  = (float*)alloc((size_t)N_MOLS * 4);
  if ((size_t)(w - (char*)d_ws) > ws_size) return;

  const ushort_t* NU = nullptr; const int* NI = nullptr;

  // ---- one-time converts ----
  f32_to_f16<<<N_ATOMS * D_IN / 4 / 256, 256, 0, stream>>>(atoms, atoms_h, N_ATOMS * D_IN / 4);
  transpose_w<<<DD * 1280 / 256, 256, 0, stream>>>(W_e, Wte, 1280);
  transpose_w<<<DD * 1024 / 256, 256, 0, stream>>>(W_v, Wtv, 1024);
  transpose_w<<<DD * 1024 / 256, 256, 0, stream>>>(W_u, Wtu, 1024);
  transpose_w<<<DD * D_IN / 256, 256, 0, stream>>>(W_fv, Wtfv, D_IN);
  transpose_w<<<DD * D_IN / 256, 256, 0, stream>>>(W_fu, Wtfu, D_IN);

  // ---- init embeddings ----
  hipMemsetAsync(msum, 0, (size_t)N_MOLS * D_IN * 4 + 4096 + N_MOLS * 4, stream);
  mol_accum<<<N_ATOMS * 32 / 256, 256, 0, stream>>>(atoms, atom_mol, msum, cnt);
  mol_mean_h<<<N_MOLS * 32 / 256, 256, 0, stream>>>(msum, cnt, mmean);
  init_he0_k<<<N_BONDS * 64 / 256, 256, 0, stream>>>(bond_orders, W_fe, he0, he);
  mfma_concat_gemm<1, 128, 128><<<N_ATOMS / 128, 512, 0, stream>>>(
      atoms_h, NI, NU, NI, NU, NI, NU, NI, NU, NI, Wtfv, hv0, hv, nullptr);
  mfma_concat_gemm<1, 128, 64><<<N_MOLS / 64, 256, 0, stream>>>(
      mmean, NI, NU, NI, NU, NI, NU, NI, NU, NI, Wtfu, hu0, hu, nullptr);

  // ---- 3 message-passing iterations (all h updates in-place, full-N blocks) ----
  for (int it = 0; it < REPEAT; ++it) {
    hipMemsetAsync(ebv_f, 0, ((size_t)N_ATOMS * DD + 2 * (size_t)N_MOLS * DD) * 4, stream);
    mfma_concat_gemm<5, 256, 128><<<N_BONDS / 128, 512, 0, stream>>>(
        he, NI, he0, NI, hv, bond_src, hv, bond_dst, hu, bond_mol,
        Wte, he, nullptr, it == REPEAT - 1 ? (float*)d_out : nullptr);
    scatter_edge_h<<<N_BONDS * 64 / 256, 256, 0, stream>>>(he, bond_src, bond_dst, ebv_f);
    seg_sum_sorted<<<N_BONDS / 64, 256, 0, stream>>>(he, bond_mol, eb_f);
    f32_to_f16<<<N_ATOMS * DD / 4 / 256, 256, 0, stream>>>(ebv_f, ebv_h, N_ATOMS * DD / 4);
    mfma_concat_gemm<4, 256, 128><<<N_ATOMS / 128, 512, 0, stream>>>(
        hv, NI, hv0, NI, ebv_h, NI, hu, atom_mol, NU, NI,
        Wtv, hv, nullptr, nullptr);
    seg_sum_sorted<<<N_ATOMS / 64, 256, 0, stream>>>(hv, atom_mol, vb_f);
    f32_to_f16<<<2 * N_MOLS * DD / 4 / 256, 256, 0, stream>>>(eb_f, eb_h, 2 * N_MOLS * DD / 4);
    mfma_concat_gemm<4, 256, 64><<<N_MOLS / 64, 256, 0, stream>>>(
        hu, NI, hu0, NI, eb_h, NI, vb_h, NI, NU, NI,
        Wtu, hu, nullptr, nullptr);
  }
}

// Round 4
// 1242.919 us; speedup vs baseline: 10.3282x; 2.8768x over previous
//
#include <hip/hip_runtime.h>
#include <cstdint>
#include <cmath>

#define N_ATOMS 65536
#define N_BONDS 98304
#define N_MOLS  4096
#define D_IN    128
#define DD      256
#define REPEAT  3

typedef __attribute__((ext_vector_type(8))) short short8;   // 8 f16 = 4 VGPR (guide §3)
typedef __attribute__((ext_vector_type(4))) float f32x4;
typedef unsigned short ushort_t;

__device__ __forceinline__ unsigned short f2h(float f) {    // RNE f32->f16
  union { _Float16 h; unsigned short u; } x; x.h = (_Float16)f; return x.u;
}
__device__ __forceinline__ float h2f(unsigned short u) {
  union { unsigned short u; _Float16 h; } x; x.u = u; return (float)x.h;
}

#define GLD16(gp, lp) __builtin_amdgcn_global_load_lds( \
    (const __attribute__((address_space(1))) void*)(gp), \
    (__attribute__((address_space(3))) void*)(lp), 16, 0, 0)

// ---------------------------------------------------------------------------
// MFMA concat-gather GEMM + tanh (fp16 in, f32 acc, fp16 out [+f32 out]).
// Verified passing in R3. Full-N blocks -> in-place update race-free.
// ---------------------------------------------------------------------------
template<int NSEG, int SEGW, int BM>
__global__ __launch_bounds__(BM * 4)
void mfma_concat_gemm(const ushort_t* __restrict__ s0, const int* __restrict__ i0,
                      const ushort_t* __restrict__ s1, const int* __restrict__ i1,
                      const ushort_t* __restrict__ s2, const int* __restrict__ i2,
                      const ushort_t* __restrict__ s3, const int* __restrict__ i3,
                      const ushort_t* __restrict__ s4, const int* __restrict__ i4,
                      const ushort_t* __restrict__ Wt,
                      ushort_t* __restrict__ ob, ushort_t* __restrict__ ob2,
                      float* __restrict__ of)
{
  constexpr int NT     = BM * 4;           // threads
  constexpr int KW     = NSEG * SEGW;      // total K
  constexpr int SPS    = SEGW / 32;        // K-steps per segment
  constexpr int ABYTES = BM * 64;          // A tile bytes
  constexpr int BI     = 16384 / (NT * 16);// B stage instrs per thread

  __shared__ __align__(16) char smem[ABYTES + 16384];

  const int t      = threadIdx.x;
  const int m0     = blockIdx.x * BM;
  const int srcoff = (((t & 3) ^ ((t >> 2) & 3) ^ ((t >> 4) & 3)) << 4); // stage-side swizzled chunk
  const int toff   = t * 16;

  // per-thread gathered A-row byte offsets, one per segment
  uint32_t aoff[5];
  {
    const int rg = m0 + (t >> 2);
    const int* ips[5] = { i0, i1, i2, i3, i4 };
    #pragma unroll
    for (int s = 0; s < NSEG; ++s) {
      int idx = ips[s] ? ips[s][rg] : rg;
      aoff[s] = (uint32_t)idx * (SEGW * 2);
    }
  }

  // per-thread Wt (B) stage base pointers
  const char* wtb[4];
  #pragma unroll
  for (int i = 0; i < BI; ++i)
    wtb[i] = (const char*)Wt + (size_t)((i * (NT >> 2) + (t >> 2)) * KW) * 2 + srcoff;

  f32x4 acc[4][4];
  const f32x4 z = {0.f, 0.f, 0.f, 0.f};
  #pragma unroll
  for (int a = 0; a < 4; ++a)
    #pragma unroll
    for (int b = 0; b < 4; ++b) acc[a][b] = z;

  const int l   = t & 63;
  const int wid = t >> 6;
  const int wr  = wid >> 2;                 // 0..BM/64-1
  const int wc  = wid & 3;                  // 0..3 (col strip of 64)
  const int swz = (((l >> 4) ^ (l & 3) ^ ((l >> 2) & 3)) << 4); // read-side swizzled chunk
  const int aro = wr * 4096 + (l & 15) * 64 + swz;
  const int bro = ABYTES + wc * 4096 + (l & 15) * 64 + swz;

  int kt = 0;
  #pragma unroll
  for (int seg = 0; seg < NSEG; ++seg) {
    const ushort_t* sp = seg == 0 ? s0 : seg == 1 ? s1 : seg == 2 ? s2 : seg == 3 ? s3 : s4;
    const char* arow = (const char*)sp + aoff[seg];
    for (int sub = 0; sub < SPS; ++sub, ++kt) {
      // stage A (1 x 16B/thread) and B (BI x 16B/thread) via global_load_lds
      GLD16(arow + sub * 64 + srcoff, smem + toff);
      #pragma unroll
      for (int i = 0; i < BI; ++i)
        GLD16(wtb[i] + (size_t)kt * 64, smem + ABYTES + i * (NT * 16) + toff);
      __syncthreads();                       // compiler drains vmcnt before barrier

      short8 af[4], bfv[4];
      #pragma unroll
      for (int mf = 0; mf < 4; ++mf) af[mf]  = *(const short8*)(smem + aro + mf * 1024);
      #pragma unroll
      for (int nf = 0; nf < 4; ++nf) bfv[nf] = *(const short8*)(smem + bro + nf * 1024);
      #pragma unroll
      for (int mf = 0; mf < 4; ++mf)
        #pragma unroll
        for (int nf = 0; nf < 4; ++nf)
          acc[mf][nf] = __builtin_amdgcn_mfma_f32_16x16x32_f16(af[mf], bfv[nf], acc[mf][nf], 0, 0, 0);
      __syncthreads();                       // protect LDS before next stage
    }
  }

  // epilogue: C/D layout col=lane&15, row=(lane>>4)*4+reg (m89-verified, dtype-independent)
  const int colb = wc * 64 + (l & 15);
  const int rowb = m0 + wr * 64 + ((l >> 4) << 2);
  #pragma unroll
  for (int mf = 0; mf < 4; ++mf) {
    #pragma unroll
    for (int nf = 0; nf < 4; ++nf) {
      f32x4 d = acc[mf][nf];
      #pragma unroll
      for (int r = 0; r < 4; ++r) {
        float v = tanhf(d[r]);
        size_t o = (size_t)(rowb + mf * 16 + r) * DD + colb + nf * 16;
        unsigned short hv16 = f2h(v);
        ob[o] = hv16;
        if (ob2) ob2[o] = hv16;
        if (of)  of[o]  = v;
      }
    }
  }
}

// -------------------------- helper kernels ---------------------------------

__global__ __launch_bounds__(256)
void f32_to_f16(const float* __restrict__ in, ushort_t* __restrict__ out, int n4) {
  int t = blockIdx.x * 256 + threadIdx.x;
  if (t >= n4) return;
  float4 v = ((const float4*)in)[t];
  ushort4 o; o.x = f2h(v.x); o.y = f2h(v.y); o.z = f2h(v.z); o.w = f2h(v.w);
  ((ushort4*)out)[t] = o;
}

// in [K][256] f32  ->  out [256][K] f16
__global__ __launch_bounds__(256)
void transpose_w(const float* __restrict__ in, ushort_t* __restrict__ out, int K) {
  int t = blockIdx.x * 256 + threadIdx.x;   // t = n*K + k
  int n = t / K, k = t - n * K;
  out[t] = f2h(in[(size_t)k * DD + n]);
}

__global__ __launch_bounds__(256)
void init_he0_k(const float* __restrict__ bo, const float* __restrict__ wfe,
                ushort_t* __restrict__ he0, ushort_t* __restrict__ he) {
  int t = blockIdx.x * 256 + threadIdx.x;   // N_BONDS*64
  int b = t >> 6, c = (t & 63) << 2;
  float o = bo[b];
  float4 w = *(const float4*)&wfe[c];
  ushort4 v;
  v.x = f2h(tanhf(o * w.x)); v.y = f2h(tanhf(o * w.y));
  v.z = f2h(tanhf(o * w.z)); v.w = f2h(tanhf(o * w.w));
  size_t idx = ((size_t)b * DD + c) >> 2;
  ((ushort4*)he0)[idx] = v; ((ushort4*)he)[idx] = v;
}

__global__ __launch_bounds__(256)
void mol_accum(const float* __restrict__ atoms, const int* __restrict__ amol,
               float* __restrict__ msum, float* __restrict__ cnt) {
  int t = blockIdx.x * 256 + threadIdx.x;   // N_ATOMS*32
  int a = t >> 5, c = (t & 31) << 2;
  float4 v = *(const float4*)&atoms[(size_t)a * D_IN + c];
  int m = amol[a];
  float* p = &msum[(size_t)m * D_IN + c];
  unsafeAtomicAdd(p + 0, v.x); unsafeAtomicAdd(p + 1, v.y);
  unsafeAtomicAdd(p + 2, v.z); unsafeAtomicAdd(p + 3, v.w);
  if ((t & 31) == 0) unsafeAtomicAdd(&cnt[m], 1.0f);
}

__global__ __launch_bounds__(256)
void mol_mean_h(const float* __restrict__ msum, const float* __restrict__ cnt,
                ushort_t* __restrict__ mmean) {
  int t = blockIdx.x * 256 + threadIdx.x;   // N_MOLS*32
  int m = t >> 5, c = (t & 31) << 2;
  float inv = 1.0f / fmaxf(cnt[m], 1.0f);
  float4 v = *(const float4*)&msum[(size_t)m * D_IN + c];
  ushort4 o; o.x = f2h(v.x * inv); o.y = f2h(v.y * inv);
  o.z = f2h(v.z * inv); o.w = f2h(v.w * inv);
  ((ushort4*)mmean)[((size_t)m * D_IN + c) >> 2] = o;
}

// ---- CSR incidence build (bond endpoints are static per call) -------------

__global__ __launch_bounds__(256)
void count_deg(const int* __restrict__ src, const int* __restrict__ dst,
               int* __restrict__ deg) {
  int b = blockIdx.x * 256 + threadIdx.x;
  if (b >= N_BONDS) return;
  atomicAdd(&deg[src[b]], 1);
  atomicAdd(&deg[dst[b]], 1);
}

// single-block exclusive scan of deg[65536] -> rowptr[65537] and cursor copy
__global__ __launch_bounds__(256)
void scan_deg(const int* __restrict__ deg, int* __restrict__ rowptr,
              int* __restrict__ cursor) {
  __shared__ int partial[256];
  int t = threadIdx.x;
  int base = t * 256;
  int s = 0;
  for (int i = 0; i < 256; ++i) s += deg[base + i];
  partial[t] = s;
  __syncthreads();
  if (t == 0) {
    int acc = 0;
    for (int i = 0; i < 256; ++i) { int v = partial[i]; partial[i] = acc; acc += v; }
    rowptr[N_ATOMS] = acc;
  }
  __syncthreads();
  int acc = partial[t];
  for (int i = 0; i < 256; ++i) {
    rowptr[base + i] = acc; cursor[base + i] = acc;
    acc += deg[base + i];
  }
}

__global__ __launch_bounds__(256)
void fill_csr(const int* __restrict__ src, const int* __restrict__ dst,
              int* __restrict__ cursor, int* __restrict__ list) {
  int b = blockIdx.x * 256 + threadIdx.x;
  if (b >= N_BONDS) return;
  int p = atomicAdd(&cursor[src[b]], 1); list[p] = b;
  int q = atomicAdd(&cursor[dst[b]], 1); list[q] = b;
}

// e_bar_v[a] = sum_{b in inc(a)} h_e[b]; one wave per atom (uniform loop),
// 64 lanes x 4 cols; f32 accumulate, write f16 directly (GEMM input).
__global__ __launch_bounds__(256)
void gather_ebv(const ushort_t* __restrict__ he, const int* __restrict__ rowptr,
                const int* __restrict__ list, ushort_t* __restrict__ ebv_h) {
  int t = blockIdx.x * 256 + threadIdx.x;   // N_ATOMS*64 threads
  int a = t >> 6, c = (t & 63) << 2;
  int s = rowptr[a], e = rowptr[a + 1];
  float a0 = 0.f, a1 = 0.f, a2 = 0.f, a3 = 0.f;
  for (int i = s; i < e; ++i) {
    int b = list[i];                        // wave-uniform broadcast
    ushort4 v = *(const ushort4*)&he[(size_t)b * DD + c];
    a0 += h2f(v.x); a1 += h2f(v.y); a2 += h2f(v.z); a3 += h2f(v.w);
  }
  ushort4 o; o.x = f2h(a0); o.y = f2h(a1); o.z = f2h(a2); o.w = f2h(a3);
  ((ushort4*)ebv_h)[((size_t)a * DD + c) >> 2] = o;
}

// out[ids[r]] += x[r] for SORTED ids: run-compress in registers, flush on change.
__global__ __launch_bounds__(256)
void seg_sum_sorted(const ushort_t* __restrict__ x, const int* __restrict__ ids,
                    float* __restrict__ out) {
  __shared__ int sid[64];
  int r0 = blockIdx.x * 64;
  int c  = threadIdx.x;                     // 256 threads = 256 cols
  if (c < 64) sid[c] = ids[r0 + c];
  __syncthreads();
  float acc = 0.f; int prev = sid[0];
  const ushort_t* p = x + (size_t)r0 * DD + c;
  for (int r = 0; r < 64; ++r, p += DD) {
    int id = sid[r];                        // wave-uniform
    if (id != prev) { unsafeAtomicAdd(&out[(size_t)prev * DD + c], acc); acc = 0.f; prev = id; }
    acc += h2f(*p);
  }
  unsafeAtomicAdd(&out[(size_t)prev * DD + c], acc);
}

// ---------------------------------------------------------------------------

extern "C" void kernel_launch(void* const* d_in, const int* in_sizes, int n_in,
                              void* d_out, int out_size, void* d_ws, size_t ws_size,
                              hipStream_t stream)
{
  const float* atoms       = (const float*)d_in[0];
  const float* bond_orders = (const float*)d_in[1];
  const int*   bond_src    = (const int*)d_in[2];
  const int*   bond_dst    = (const int*)d_in[3];
  const int*   atom_mol    = (const int*)d_in[4];
  const int*   bond_mol    = (const int*)d_in[5];
  const float* W_fe        = (const float*)d_in[6];
  const float* W_fv        = (const float*)d_in[7];
  const float* W_fu        = (const float*)d_in[8];
  const float* W_e         = (const float*)d_in[9];
  const float* W_v         = (const float*)d_in[10];
  const float* W_u         = (const float*)d_in[11];

  char* w = (char*)d_ws;
  auto alloc = [&](size_t bytes) { char* p = w; w += (bytes + 255) & ~(size_t)255; return p; };

  ushort_t* atoms_h  = (ushort_t*)alloc((size_t)N_ATOMS * D_IN * 2);
  ushort_t* he0  = (ushort_t*)alloc((size_t)N_BONDS * DD * 2);
  ushort_t* he   = (ushort_t*)alloc((size_t)N_BONDS * DD * 2);
  ushort_t* hv0  = (ushort_t*)alloc((size_t)N_ATOMS * DD * 2);
  ushort_t* hv   = (ushort_t*)alloc((size_t)N_ATOMS * DD * 2);
  ushort_t* hu0  = (ushort_t*)alloc((size_t)N_MOLS * DD * 2);
  ushort_t* hu   = (ushort_t*)alloc((size_t)N_MOLS * DD * 2);
  ushort_t* mmean= (ushort_t*)alloc((size_t)N_MOLS * D_IN * 2);
  ushort_t* Wte  = (ushort_t*)alloc((size_t)DD * 1280 * 2);
  ushort_t* Wtv  = (ushort_t*)alloc((size_t)DD * 1024 * 2);
  ushort_t* Wtu  = (ushort_t*)alloc((size_t)DD * 1024 * 2);
  ushort_t* Wtfv = (ushort_t*)alloc((size_t)DD * D_IN * 2);
  ushort_t* Wtfu = (ushort_t*)alloc((size_t)DD * D_IN * 2);
  float* eb_f  = (float*)alloc((size_t)N_MOLS * DD * 4);        // eb,vb contiguous
  float* vb_f  = (float*)alloc((size_t)N_MOLS * DD * 4);
  ushort_t* ebv_h = (ushort_t*)alloc((size_t)N_ATOMS * DD * 2);
  ushort_t* eb_h  = (ushort_t*)alloc((size_t)N_MOLS * DD * 2);  // eb_h,vb_h contiguous
  ushort_t* vb_h  = (ushort_t*)alloc((size_t)N_MOLS * DD * 2);
  float* msum = (float*)alloc((size_t)N_MOLS * D_IN * 4);       // msum,cnt contiguous
  float* cnt  = (float*)alloc((size_t)N_MOLS * 4);
  int* deg    = (int*)alloc((size_t)N_ATOMS * 4);
  int* rowptr = (int*)alloc((size_t)(N_ATOMS + 1) * 4);
  int* cursor = (int*)alloc((size_t)N_ATOMS * 4);
  int* list   = (int*)alloc((size_t)2 * N_BONDS * 4);
  if ((size_t)(w - (char*)d_ws) > ws_size) return;

  const ushort_t* NU = nullptr; const int* NI = nullptr;

  // ---- one-time converts + CSR build ----
  f32_to_f16<<<N_ATOMS * D_IN / 4 / 256, 256, 0, stream>>>(atoms, atoms_h, N_ATOMS * D_IN / 4);
  transpose_w<<<DD * 1280 / 256, 256, 0, stream>>>(W_e, Wte, 1280);
  transpose_w<<<DD * 1024 / 256, 256, 0, stream>>>(W_v, Wtv, 1024);
  transpose_w<<<DD * 1024 / 256, 256, 0, stream>>>(W_u, Wtu, 1024);
  transpose_w<<<DD * D_IN / 256, 256, 0, stream>>>(W_fv, Wtfv, D_IN);
  transpose_w<<<DD * D_IN / 256, 256, 0, stream>>>(W_fu, Wtfu, D_IN);
  hipMemsetAsync(deg, 0, (size_t)N_ATOMS * 4, stream);
  count_deg<<<(N_BONDS + 255) / 256, 256, 0, stream>>>(bond_src, bond_dst, deg);
  scan_deg<<<1, 256, 0, stream>>>(deg, rowptr, cursor);
  fill_csr<<<(N_BONDS + 255) / 256, 256, 0, stream>>>(bond_src, bond_dst, cursor, list);

  // ---- init embeddings ----
  hipMemsetAsync(msum, 0, (size_t)N_MOLS * D_IN * 4 + 4096 + N_MOLS * 4, stream);
  mol_accum<<<N_ATOMS * 32 / 256, 256, 0, stream>>>(atoms, atom_mol, msum, cnt);
  mol_mean_h<<<N_MOLS * 32 / 256, 256, 0, stream>>>(msum, cnt, mmean);
  init_he0_k<<<N_BONDS * 64 / 256, 256, 0, stream>>>(bond_orders, W_fe, he0, he);
  mfma_concat_gemm<1, 128, 128><<<N_ATOMS / 128, 512, 0, stream>>>(
      atoms_h, NI, NU, NI, NU, NI, NU, NI, NU, NI, Wtfv, hv0, hv, nullptr);
  mfma_concat_gemm<1, 128, 64><<<N_MOLS / 64, 256, 0, stream>>>(
      mmean, NI, NU, NI, NU, NI, NU, NI, NU, NI, Wtfu, hu0, hu, nullptr);

  // ---- 3 message-passing iterations (all h updates in-place, full-N blocks) ----
  for (int it = 0; it < REPEAT; ++it) {
    hipMemsetAsync(eb_f, 0, (size_t)2 * N_MOLS * DD * 4, stream);
    mfma_concat_gemm<5, 256, 128><<<N_BONDS / 128, 512, 0, stream>>>(
        he, NI, he0, NI, hv, bond_src, hv, bond_dst, hu, bond_mol,
        Wte, he, nullptr, it == REPEAT - 1 ? (float*)d_out : nullptr);
    gather_ebv<<<N_ATOMS * 64 / 256, 256, 0, stream>>>(he, rowptr, list, ebv_h);
    seg_sum_sorted<<<N_BONDS / 64, 256, 0, stream>>>(he, bond_mol, eb_f);
    mfma_concat_gemm<4, 256, 128><<<N_ATOMS / 128, 512, 0, stream>>>(
        hv, NI, hv0, NI, ebv_h, NI, hu, atom_mol, NU, NI,
        Wtv, hv, nullptr, nullptr);
    seg_sum_sorted<<<N_ATOMS / 64, 256, 0, stream>>>(hv, atom_mol, vb_f);
    f32_to_f16<<<2 * N_MOLS * DD / 4 / 256, 256, 0, stream>>>(eb_f, eb_h, 2 * N_MOLS * DD / 4);
    mfma_concat_gemm<4, 256, 64><<<N_MOLS / 64, 256, 0, stream>>>(
        hu, NI, hu0, NI, eb_h, NI, vb_h, NI, NU, NI,
        Wtu, hu, nullptr, nullptr);
  }
}

// Round 5
// 1086.555 us; speedup vs baseline: 11.8145x; 1.1439x over previous
//
#include <hip/hip_runtime.h>
#include <cstdint>
#include <cmath>

#define N_ATOMS 65536
#define N_BONDS 98304
#define N_MOLS  4096
#define D_IN    128
#define DD      256
#define REPEAT  3

typedef __attribute__((ext_vector_type(8))) short short8;   // 8 f16 = 4 VGPR
typedef __attribute__((ext_vector_type(4))) float f32x4;
typedef unsigned short ushort_t;

__device__ __forceinline__ unsigned short f2h(float f) {    // RNE f32->f16
  union { _Float16 h; unsigned short u; } x; x.h = (_Float16)f; return x.u;
}
__device__ __forceinline__ float h2f(unsigned short u) {
  union { unsigned short u; _Float16 h; } x; x.u = u; return (float)x.h;
}

#define GLD16(gp, lp) __builtin_amdgcn_global_load_lds( \
    (const __attribute__((address_space(1))) void*)(gp), \
    (__attribute__((address_space(3))) void*)(lp), 16, 0, 0)

// ---------------------------------------------------------------------------
// MFMA concat-gather GEMM + tanh (fp16 in, f32 acc, fp16 out [+f32 out]).
// R5: double-buffered LDS, prefetch next K-tile before compute, ONE barrier
// per K-step (T3-minimum 2-phase). Segment indices compile-time via unrolled
// outer loop + peeled cross-segment prefetch. Swizzle unchanged (verified).
// Full-N blocks (BN=256) -> in-place update race-free.
// ---------------------------------------------------------------------------
template<int NSEG, int SEGW, int BM>
__global__ __launch_bounds__(BM * 4)
void mfma_concat_gemm(const ushort_t* __restrict__ s0, const int* __restrict__ i0,
                      const ushort_t* __restrict__ s1, const int* __restrict__ i1,
                      const ushort_t* __restrict__ s2, const int* __restrict__ i2,
                      const ushort_t* __restrict__ s3, const int* __restrict__ i3,
                      const ushort_t* __restrict__ s4, const int* __restrict__ i4,
                      const ushort_t* __restrict__ Wt,
                      ushort_t* __restrict__ ob, ushort_t* __restrict__ ob2,
                      float* __restrict__ of)
{
  constexpr int NT     = BM * 4;            // threads
  constexpr int KW     = NSEG * SEGW;       // total K
  constexpr int SPS    = SEGW / 32;         // K-steps per segment
  constexpr int ABYTES = BM * 64;           // A tile bytes
  constexpr int TILE   = ABYTES + 16384;    // one K-step tile (A + B)
  constexpr int BI     = 16384 / (NT * 16); // B stage instrs per thread

  __shared__ __align__(16) char smem[2 * TILE];

  const int t      = threadIdx.x;
  const int m0     = blockIdx.x * BM;
  const int srcoff = (((t & 3) ^ ((t >> 2) & 3) ^ ((t >> 4) & 3)) << 4); // stage-side swizzled chunk
  const int toff   = t * 16;

  // per-thread gathered A-row pointers, one per segment (static-indexed)
  const char* arows[5];
  {
    const int rg = m0 + (t >> 2);
    const int* ips[5] = { i0, i1, i2, i3, i4 };
    const ushort_t* sps[5] = { s0, s1, s2, s3, s4 };
    #pragma unroll
    for (int s = 0; s < NSEG; ++s) {
      int idx = ips[s] ? ips[s][rg] : rg;
      arows[s] = (const char*)sps[s] + (size_t)idx * (SEGW * 2);
    }
  }

  // per-thread Wt (B) stage base pointers
  const char* wtb[4];
  #pragma unroll
  for (int i = 0; i < BI; ++i)
    wtb[i] = (const char*)Wt + (size_t)((i * (NT >> 2) + (t >> 2)) * KW) * 2 + srcoff;

  f32x4 acc[4][4];
  const f32x4 z = {0.f, 0.f, 0.f, 0.f};
  #pragma unroll
  for (int a = 0; a < 4; ++a)
    #pragma unroll
    for (int b = 0; b < 4; ++b) acc[a][b] = z;

  const int l   = t & 63;
  const int wid = t >> 6;
  const int wr  = wid >> 2;                 // 0..BM/64-1
  const int wc  = wid & 3;                  // 0..3 (col strip of 64)
  const int swz = (((l >> 4) ^ (l & 3) ^ ((l >> 2) & 3)) << 4); // read-side swizzled chunk
  const int aro = wr * 4096 + (l & 15) * 64 + swz;
  const int bro = ABYTES + wc * 4096 + (l & 15) * 64 + swz;

  // stage K-step (segS, sub) into LDS at byte base `db` (segS constant-folded)
  auto stage_tile = [&](int segS, int sub, int db) {
    GLD16(arows[segS] + sub * 64 + srcoff, smem + db + toff);
    const int kt = segS * SPS + sub;
    #pragma unroll
    for (int i = 0; i < BI; ++i)
      GLD16(wtb[i] + (size_t)kt * 64, smem + db + ABYTES + i * (NT * 16) + toff);
  };
  auto compute = [&](int sb) {
    short8 af[4], bfv[4];
    #pragma unroll
    for (int mf = 0; mf < 4; ++mf) af[mf]  = *(const short8*)(smem + sb + aro + mf * 1024);
    #pragma unroll
    for (int nf = 0; nf < 4; ++nf) bfv[nf] = *(const short8*)(smem + sb + bro + nf * 1024);
    #pragma unroll
    for (int mf = 0; mf < 4; ++mf)
      #pragma unroll
      for (int nf = 0; nf < 4; ++nf)
        acc[mf][nf] = __builtin_amdgcn_mfma_f32_16x16x32_f16(af[mf], bfv[nf], acc[mf][nf], 0, 0, 0);
  };

  // prologue: stage first tile into buffer 0
  stage_tile(0, 0, 0);
  __syncthreads();                           // drains vmcnt(0)

  int cur = 0;
  #pragma unroll
  for (int seg = 0; seg < NSEG; ++seg) {
    for (int sub = 0; sub < SPS; ++sub) {    // runtime inner loop (SPS even)
      const int nb = (cur ^ 1) * TILE;
      if (sub + 1 < SPS)            stage_tile(seg, sub + 1, nb);     // same seg (static)
      else if (seg + 1 < NSEG)      stage_tile(seg + 1, 0, nb);       // next seg (static)
      compute(cur * TILE);
      __syncthreads();              // drains prefetch vmcnt + closes LDS read window
      cur ^= 1;
    }
  }

  // epilogue: C/D layout col=lane&15, row=(lane>>4)*4+reg (m89-verified)
  const int colb = wc * 64 + (l & 15);
  const int rowb = m0 + wr * 64 + ((l >> 4) << 2);
  #pragma unroll
  for (int mf = 0; mf < 4; ++mf) {
    #pragma unroll
    for (int nf = 0; nf < 4; ++nf) {
      f32x4 d = acc[mf][nf];
      #pragma unroll
      for (int r = 0; r < 4; ++r) {
        float v = tanhf(d[r]);
        size_t o = (size_t)(rowb + mf * 16 + r) * DD + colb + nf * 16;
        unsigned short hv16 = f2h(v);
        ob[o] = hv16;
        if (ob2) ob2[o] = hv16;
        if (of)  of[o]  = v;
      }
    }
  }
}

// -------------------------- helper kernels ---------------------------------

__global__ __launch_bounds__(256)
void f32_to_f16(const float* __restrict__ in, ushort_t* __restrict__ out, int n4) {
  int t = blockIdx.x * 256 + threadIdx.x;
  if (t >= n4) return;
  float4 v = ((const float4*)in)[t];
  ushort4 o; o.x = f2h(v.x); o.y = f2h(v.y); o.z = f2h(v.z); o.w = f2h(v.w);
  ((ushort4*)out)[t] = o;
}

// in [K][256] f32  ->  out [256][K] f16
__global__ __launch_bounds__(256)
void transpose_w(const float* __restrict__ in, ushort_t* __restrict__ out, int K) {
  int t = blockIdx.x * 256 + threadIdx.x;   // t = n*K + k
  int n = t / K, k = t - n * K;
  out[t] = f2h(in[(size_t)k * DD + n]);
}

__global__ __launch_bounds__(256)
void init_he0_k(const float* __restrict__ bo, const float* __restrict__ wfe,
                ushort_t* __restrict__ he0, ushort_t* __restrict__ he) {
  int t = blockIdx.x * 256 + threadIdx.x;   // N_BONDS*64
  int b = t >> 6, c = (t & 63) << 2;
  float o = bo[b];
  float4 w = *(const float4*)&wfe[c];
  ushort4 v;
  v.x = f2h(tanhf(o * w.x)); v.y = f2h(tanhf(o * w.y));
  v.z = f2h(tanhf(o * w.z)); v.w = f2h(tanhf(o * w.w));
  size_t idx = ((size_t)b * DD + c) >> 2;
  ((ushort4*)he0)[idx] = v; ((ushort4*)he)[idx] = v;
}

// msum[mol] += atoms[a], cnt[mol] += 1 -- SORTED atom_mol: run-compress,
// one atomic per (segment boundary x col) instead of per (atom x col).
__global__ __launch_bounds__(128)
void mol_accum_sorted(const float* __restrict__ atoms, const int* __restrict__ amol,
                      float* __restrict__ msum, float* __restrict__ cnt) {
  __shared__ int sid[64];
  int r0 = blockIdx.x * 64;
  int c  = threadIdx.x;                     // 128 threads = 128 cols
  if (c < 64) sid[c] = amol[r0 + c];
  __syncthreads();
  float acc = 0.f; int prev = sid[0]; int run = 0;
  const float* p = atoms + (size_t)r0 * D_IN + c;
  for (int r = 0; r < 64; ++r, p += D_IN) {
    int id = sid[r];                        // wave-uniform
    if (id != prev) {
      unsafeAtomicAdd(&msum[(size_t)prev * D_IN + c], acc);
      if (c == 0) unsafeAtomicAdd(&cnt[prev], (float)run);
      acc = 0.f; run = 0; prev = id;
    }
    acc += *p; run += 1;
  }
  unsafeAtomicAdd(&msum[(size_t)prev * D_IN + c], acc);
  if (c == 0) unsafeAtomicAdd(&cnt[prev], (float)run);
}

__global__ __launch_bounds__(256)
void mol_mean_h(const float* __restrict__ msum, const float* __restrict__ cnt,
                ushort_t* __restrict__ mmean) {
  int t = blockIdx.x * 256 + threadIdx.x;   // N_MOLS*32
  int m = t >> 5, c = (t & 31) << 2;
  float inv = 1.0f / fmaxf(cnt[m], 1.0f);
  float4 v = *(const float4*)&msum[(size_t)m * D_IN + c];
  ushort4 o; o.x = f2h(v.x * inv); o.y = f2h(v.y * inv);
  o.z = f2h(v.z * inv); o.w = f2h(v.w * inv);
  ((ushort4*)mmean)[((size_t)m * D_IN + c) >> 2] = o;
}

// ---- CSR incidence build (bond endpoints are static per call) -------------

__global__ __launch_bounds__(256)
void count_deg(const int* __restrict__ src, const int* __restrict__ dst,
               int* __restrict__ deg) {
  int b = blockIdx.x * 256 + threadIdx.x;
  if (b >= N_BONDS) return;
  atomicAdd(&deg[src[b]], 1);
  atomicAdd(&deg[dst[b]], 1);
}

// single-block exclusive scan of deg[65536] -> rowptr[65537] and cursor copy
__global__ __launch_bounds__(256)
void scan_deg(const int* __restrict__ deg, int* __restrict__ rowptr,
              int* __restrict__ cursor) {
  __shared__ int partial[256];
  int t = threadIdx.x;
  int base = t * 256;
  int s = 0;
  for (int i = 0; i < 256; ++i) s += deg[base + i];
  partial[t] = s;
  __syncthreads();
  if (t == 0) {
    int acc = 0;
    for (int i = 0; i < 256; ++i) { int v = partial[i]; partial[i] = acc; acc += v; }
    rowptr[N_ATOMS] = acc;
  }
  __syncthreads();
  int acc = partial[t];
  for (int i = 0; i < 256; ++i) {
    rowptr[base + i] = acc; cursor[base + i] = acc;
    acc += deg[base + i];
  }
}

__global__ __launch_bounds__(256)
void fill_csr(const int* __restrict__ src, const int* __restrict__ dst,
              int* __restrict__ cursor, int* __restrict__ list) {
  int b = blockIdx.x * 256 + threadIdx.x;
  if (b >= N_BONDS) return;
  int p = atomicAdd(&cursor[src[b]], 1); list[p] = b;
  int q = atomicAdd(&cursor[dst[b]], 1); list[q] = b;
}

// e_bar_v[a] = sum_{b in inc(a)} h_e[b]; one wave per atom (uniform loop),
// 64 lanes x 4 cols; f32 accumulate, write f16 directly (GEMM input).
__global__ __launch_bounds__(256)
void gather_ebv(const ushort_t* __restrict__ he, const int* __restrict__ rowptr,
                const int* __restrict__ list, ushort_t* __restrict__ ebv_h) {
  int t = blockIdx.x * 256 + threadIdx.x;   // N_ATOMS*64 threads
  int a = t >> 6, c = (t & 63) << 2;
  int s = rowptr[a], e = rowptr[a + 1];
  float a0 = 0.f, a1 = 0.f, a2 = 0.f, a3 = 0.f;
  for (int i = s; i < e; ++i) {
    int b = list[i];                        // wave-uniform broadcast
    ushort4 v = *(const ushort4*)&he[(size_t)b * DD + c];
    a0 += h2f(v.x); a1 += h2f(v.y); a2 += h2f(v.z); a3 += h2f(v.w);
  }
  ushort4 o; o.x = f2h(a0); o.y = f2h(a1); o.z = f2h(a2); o.w = f2h(a3);
  ((ushort4*)ebv_h)[((size_t)a * DD + c) >> 2] = o;
}

// out[ids[r]] += x[r] for SORTED ids: run-compress in registers, flush on change.
__global__ __launch_bounds__(256)
void seg_sum_sorted(const ushort_t* __restrict__ x, const int* __restrict__ ids,
                    float* __restrict__ out) {
  __shared__ int sid[64];
  int r0 = blockIdx.x * 64;
  int c  = threadIdx.x;                     // 256 threads = 256 cols
  if (c < 64) sid[c] = ids[r0 + c];
  __syncthreads();
  float acc = 0.f; int prev = sid[0];
  const ushort_t* p = x + (size_t)r0 * DD + c;
  for (int r = 0; r < 64; ++r, p += DD) {
    int id = sid[r];                        // wave-uniform
    if (id != prev) { unsafeAtomicAdd(&out[(size_t)prev * DD + c], acc); acc = 0.f; prev = id; }
    acc += h2f(*p);
  }
  unsafeAtomicAdd(&out[(size_t)prev * DD + c], acc);
}

// ---------------------------------------------------------------------------

extern "C" void kernel_launch(void* const* d_in, const int* in_sizes, int n_in,
                              void* d_out, int out_size, void* d_ws, size_t ws_size,
                              hipStream_t stream)
{
  const float* atoms       = (const float*)d_in[0];
  const float* bond_orders = (const float*)d_in[1];
  const int*   bond_src    = (const int*)d_in[2];
  const int*   bond_dst    = (const int*)d_in[3];
  const int*   atom_mol    = (const int*)d_in[4];
  const int*   bond_mol    = (const int*)d_in[5];
  const float* W_fe        = (const float*)d_in[6];
  const float* W_fv        = (const float*)d_in[7];
  const float* W_fu        = (const float*)d_in[8];
  const float* W_e         = (const float*)d_in[9];
  const float* W_v         = (const float*)d_in[10];
  const float* W_u         = (const float*)d_in[11];

  char* w = (char*)d_ws;
  auto alloc = [&](size_t bytes) { char* p = w; w += (bytes + 255) & ~(size_t)255; return p; };

  ushort_t* atoms_h  = (ushort_t*)alloc((size_t)N_ATOMS * D_IN * 2);
  ushort_t* he0  = (ushort_t*)alloc((size_t)N_BONDS * DD * 2);
  ushort_t* he   = (ushort_t*)alloc((size_t)N_BONDS * DD * 2);
  ushort_t* hv0  = (ushort_t*)alloc((size_t)N_ATOMS * DD * 2);
  ushort_t* hv   = (ushort_t*)alloc((size_t)N_ATOMS * DD * 2);
  ushort_t* hu0  = (ushort_t*)alloc((size_t)N_MOLS * DD * 2);
  ushort_t* hu   = (ushort_t*)alloc((size_t)N_MOLS * DD * 2);
  ushort_t* mmean= (ushort_t*)alloc((size_t)N_MOLS * D_IN * 2);
  ushort_t* Wte  = (ushort_t*)alloc((size_t)DD * 1280 * 2);
  ushort_t* Wtv  = (ushort_t*)alloc((size_t)DD * 1024 * 2);
  ushort_t* Wtu  = (ushort_t*)alloc((size_t)DD * 1024 * 2);
  ushort_t* Wtfv = (ushort_t*)alloc((size_t)DD * D_IN * 2);
  ushort_t* Wtfu = (ushort_t*)alloc((size_t)DD * D_IN * 2);
  float* eb_f  = (float*)alloc((size_t)N_MOLS * DD * 4);        // eb,vb contiguous
  float* vb_f  = (float*)alloc((size_t)N_MOLS * DD * 4);
  ushort_t* ebv_h = (ushort_t*)alloc((size_t)N_ATOMS * DD * 2);
  ushort_t* eb_h  = (ushort_t*)alloc((size_t)N_MOLS * DD * 2);  // eb_h,vb_h contiguous
  ushort_t* vb_h  = (ushort_t*)alloc((size_t)N_MOLS * DD * 2);
  float* msum = (float*)alloc((size_t)N_MOLS * D_IN * 4);       // msum,cnt contiguous
  float* cnt  = (float*)alloc((size_t)N_MOLS * 4);
  int* deg    = (int*)alloc((size_t)N_ATOMS * 4);
  int* rowptr = (int*)alloc((size_t)(N_ATOMS + 1) * 4);
  int* cursor = (int*)alloc((size_t)N_ATOMS * 4);
  int* list   = (int*)alloc((size_t)2 * N_BONDS * 4);
  if ((size_t)(w - (char*)d_ws) > ws_size) return;

  const ushort_t* NU = nullptr; const int* NI = nullptr;

  // ---- one-time converts + CSR build ----
  f32_to_f16<<<N_ATOMS * D_IN / 4 / 256, 256, 0, stream>>>(atoms, atoms_h, N_ATOMS * D_IN / 4);
  transpose_w<<<DD * 1280 / 256, 256, 0, stream>>>(W_e, Wte, 1280);
  transpose_w<<<DD * 1024 / 256, 256, 0, stream>>>(W_v, Wtv, 1024);
  transpose_w<<<DD * 1024 / 256, 256, 0, stream>>>(W_u, Wtu, 1024);
  transpose_w<<<DD * D_IN / 256, 256, 0, stream>>>(W_fv, Wtfv, D_IN);
  transpose_w<<<DD * D_IN / 256, 256, 0, stream>>>(W_fu, Wtfu, D_IN);
  hipMemsetAsync(deg, 0, (size_t)N_ATOMS * 4, stream);
  count_deg<<<(N_BONDS + 255) / 256, 256, 0, stream>>>(bond_src, bond_dst, deg);
  scan_deg<<<1, 256, 0, stream>>>(deg, rowptr, cursor);
  fill_csr<<<(N_BONDS + 255) / 256, 256, 0, stream>>>(bond_src, bond_dst, cursor, list);

  // ---- init embeddings ----
  hipMemsetAsync(msum, 0, (size_t)(N_MOLS * D_IN + N_MOLS) * 4, stream);
  mol_accum_sorted<<<N_ATOMS / 64, 128, 0, stream>>>(atoms, atom_mol, msum, cnt);
  mol_mean_h<<<N_MOLS * 32 / 256, 256, 0, stream>>>(msum, cnt, mmean);
  init_he0_k<<<N_BONDS * 64 / 256, 256, 0, stream>>>(bond_orders, W_fe, he0, he);
  mfma_concat_gemm<1, 128, 128><<<N_ATOMS / 128, 512, 0, stream>>>(
      atoms_h, NI, NU, NI, NU, NI, NU, NI, NU, NI, Wtfv, hv0, hv, nullptr);
  mfma_concat_gemm<1, 128, 64><<<N_MOLS / 64, 256, 0, stream>>>(
      mmean, NI, NU, NI, NU, NI, NU, NI, NU, NI, Wtfu, hu0, hu, nullptr);

  // ---- 3 message-passing iterations (all h updates in-place, full-N blocks) ----
  for (int it = 0; it < REPEAT; ++it) {
    hipMemsetAsync(eb_f, 0, (size_t)2 * N_MOLS * DD * 4, stream);
    mfma_concat_gemm<5, 256, 128><<<N_BONDS / 128, 512, 0, stream>>>(
        he, NI, he0, NI, hv, bond_src, hv, bond_dst, hu, bond_mol,
        Wte, he, nullptr, it == REPEAT - 1 ? (float*)d_out : nullptr);
    gather_ebv<<<N_ATOMS * 64 / 256, 256, 0, stream>>>(he, rowptr, list, ebv_h);
    seg_sum_sorted<<<N_BONDS / 64, 256, 0, stream>>>(he, bond_mol, eb_f);
    mfma_concat_gemm<4, 256, 128><<<N_ATOMS / 128, 512, 0, stream>>>(
        hv, NI, hv0, NI, ebv_h, NI, hu, atom_mol, NU, NI,
        Wtv, hv, nullptr, nullptr);
    seg_sum_sorted<<<N_ATOMS / 64, 256, 0, stream>>>(hv, atom_mol, vb_f);
    f32_to_f16<<<2 * N_MOLS * DD / 4 / 256, 256, 0, stream>>>(eb_f, eb_h, 2 * N_MOLS * DD / 4);
    mfma_concat_gemm<4, 256, 64><<<N_MOLS / 64, 256, 0, stream>>>(
        hu, NI, hu0, NI, eb_h, NI, vb_h, NI, NU, NI,
        Wtu, hu, nullptr, nullptr);
  }
}